// Round 3
// baseline (449.145 us; speedup 1.0000x reference)
//
#include <hip/hip_runtime.h>
#include <math.h>

namespace {
constexpr int B_   = 8;
constexpr int DIM_ = 2048;
constexpr int H_   = 16;
constexpr int QLR_ = 1536;
constexpr int KVLR_= 512;
constexpr int DN_  = 128;
constexpr int DR_  = 64;
constexpr int DV_  = 128;
constexpr int TPRE_= 8191;
constexpr int CE_  = 576;    // KVLR + DR
constexpr int NCH_ = 64;     // chunks over T=8192
constexpr int CT_  = 128;    // t per chunk
constexpr int TT_  = 16;     // t per LDS tile
constexpr float EPS_ = 1e-6f;
constexpr float SCALE_ = 0.07216878364870322f; // (DN+DR)^-0.5
constexpr int KSTR_ = 516;   // kv tile LDS stride (mod 32 = 4 words -> 2-way only)
constexpr int PSTR_ = 68;    // pe tile LDS stride

// workspace layout (float offsets)
constexpr size_t WS_QLAT  = 0;
constexpr size_t WS_KVPE  = WS_QLAT  + (size_t)B_*QLR_;
constexpr size_t WS_KVNEW = WS_KVPE  + (size_t)B_*CE_;
constexpr size_t WS_PENEW = WS_KVNEW + (size_t)B_*KVLR_;
constexpr size_t WS_QRS   = WS_PENEW + (size_t)B_*DR_;
constexpr size_t WS_QNOPE = WS_QRS   + (size_t)B_;
constexpr size_t WS_QT    = WS_QNOPE + (size_t)B_*H_*DN_;   // [b][576][16]
constexpr size_t WS_MLOC  = WS_QT    + (size_t)B_*CE_*H_;
constexpr size_t WS_LLOC  = WS_MLOC  + (size_t)B_*H_*NCH_;
constexpr size_t WS_OUT2  = WS_LLOC  + (size_t)B_*H_*NCH_;
constexpr size_t WS_OPART = WS_OUT2  + (size_t)B_*DIM_;     // [b][h][chunk][512]
} // namespace

// ---------------- K1: q_latent = x@wq_a^T + b ; kvpe = x@wkv_a^T + b ----------------
__global__ __launch_bounds__(512) void mla_k1(const float* __restrict__ x,
                                              const float* __restrict__ wqa,
                                              const float* __restrict__ bqa,
                                              const float* __restrict__ wkva,
                                              const float* __restrict__ bkva,
                                              float* __restrict__ ws) {
  const int w = threadIdx.x >> 6, l = threadIdx.x & 63;
  const int r = blockIdx.x * 8 + w;  // 0..2111
  const float* W; const float* bias; float* out; int rr; int ostride;
  if (r < QLR_) { W = wqa;  bias = bqa;  out = ws + WS_QLAT; rr = r;        ostride = QLR_; }
  else          { W = wkva; bias = bkva; out = ws + WS_KVPE; rr = r - QLR_; ostride = CE_;  }
  const float4* wp = (const float4*)(W + (size_t)rr * DIM_);
  const float4* x4 = (const float4*)x;
  float4 wv[8];
#pragma unroll
  for (int j = 0; j < 8; ++j) wv[j] = wp[l + 64 * j];  // independent weight stream first
  float acc[B_];
#pragma unroll
  for (int b = 0; b < B_; ++b) acc[b] = 0.f;
#pragma unroll
  for (int b = 0; b < B_; ++b) {
#pragma unroll
    for (int j = 0; j < 8; ++j) {
      const float4 xv = x4[b * (DIM_ / 4) + l + 64 * j];
      acc[b] = fmaf(wv[j].x, xv.x, fmaf(wv[j].y, xv.y, fmaf(wv[j].z, xv.z, fmaf(wv[j].w, xv.w, acc[b]))));
    }
  }
#pragma unroll
  for (int b = 0; b < B_; ++b)
#pragma unroll
    for (int s = 32; s; s >>= 1) acc[b] += __shfl_xor(acc[b], s);
  if (l == 0) {
    const float b0 = bias[rr];
#pragma unroll
    for (int b = 0; b < B_; ++b) out[b * ostride + rr] = acc[b] + b0;
  }
}

// ---------------- K2: kv rms-norm + k_pe rope + q rms scales ----------------
__global__ __launch_bounds__(256) void mla_k2(const float* __restrict__ kvnw,
                                              const float* __restrict__ fcos,
                                              const float* __restrict__ fsin,
                                              float* __restrict__ ws) {
  const int tid = threadIdx.x;
  const int b = tid >> 5, i = tid & 31;
  const float* kvpe = ws + WS_KVPE + b * CE_;
  float ss = 0.f;
#pragma unroll
  for (int j = 0; j < KVLR_ / 32; ++j) { const float v = kvpe[i + 32 * j]; ss = fmaf(v, v, ss); }
#pragma unroll
  for (int s = 16; s; s >>= 1) ss += __shfl_xor(ss, s, 32);
  const float scale = 1.0f / sqrtf(ss / (float)KVLR_ + EPS_);
  float* kvn = ws + WS_KVNEW + b * KVLR_;
#pragma unroll
  for (int j = 0; j < KVLR_ / 32; ++j) {
    const int c = i + 32 * j;
    kvn[c] = kvpe[c] * kvnw[c] * scale;
  }
  { // rope new k_pe
    const float xr = kvpe[KVLR_ + 2 * i], xi = kvpe[KVLR_ + 2 * i + 1];
    const float c = fcos[i], s = fsin[i];
    float* pen = ws + WS_PENEW + b * DR_;
    pen[2 * i]     = xr * c - xi * s;
    pen[2 * i + 1] = xr * s + xi * c;
  }
  { // q latent rms scale per batch
    const float* p = ws + WS_QLAT + b * QLR_;
    float sq = 0.f;
#pragma unroll
    for (int j = 0; j < QLR_ / 32; ++j) { const float v = p[i + 32 * j]; sq = fmaf(v, v, sq); }
#pragma unroll
    for (int s = 16; s; s >>= 1) sq += __shfl_xor(sq, s, 32);
    if (i == 0) ws[WS_QRS + b] = 1.0f / sqrtf(sq / (float)QLR_ + EPS_);
  }
}

// ---------------- K3: q = rms(q_lat)*g @ wq_b^T + b ; split nope / rope(pe) ----------------
__global__ __launch_bounds__(256) void mla_k3(const float* __restrict__ qnw,
                                              const float* __restrict__ wqb,
                                              const float* __restrict__ bqb,
                                              const float* __restrict__ fcos,
                                              const float* __restrict__ fsin,
                                              float* __restrict__ ws) {
  const int w = threadIdx.x >> 6, l = threadIdx.x & 63;
  const int r0 = blockIdx.x * 8 + w * 2;  // 0..3070
  const float4* w0p = (const float4*)(wqb + (size_t)r0 * QLR_);
  const float4* w1p = (const float4*)(wqb + (size_t)(r0 + 1) * QLR_);
  const float4* g4  = (const float4*)qnw;
  const float4* x4  = (const float4*)(ws + WS_QLAT);
  float4 wg0[6], wg1[6];
#pragma unroll
  for (int j = 0; j < 6; ++j) {       // preload weights*gain
    const int c4 = l + 64 * j;
    const float4 a = w0p[c4], bb = w1p[c4], g = g4[c4];
    wg0[j].x = a.x * g.x; wg0[j].y = a.y * g.y; wg0[j].z = a.z * g.z; wg0[j].w = a.w * g.w;
    wg1[j].x = bb.x * g.x; wg1[j].y = bb.y * g.y; wg1[j].z = bb.z * g.z; wg1[j].w = bb.w * g.w;
  }
  float acc0[B_], acc1[B_];
#pragma unroll
  for (int b = 0; b < B_; ++b) { acc0[b] = 0.f; acc1[b] = 0.f; }
#pragma unroll
  for (int b = 0; b < B_; ++b) {
#pragma unroll
    for (int j = 0; j < 6; ++j) {
      const float4 xv = x4[b * (QLR_ / 4) + l + 64 * j];
      acc0[b] = fmaf(wg0[j].x, xv.x, fmaf(wg0[j].y, xv.y, fmaf(wg0[j].z, xv.z, fmaf(wg0[j].w, xv.w, acc0[b]))));
      acc1[b] = fmaf(wg1[j].x, xv.x, fmaf(wg1[j].y, xv.y, fmaf(wg1[j].z, xv.z, fmaf(wg1[j].w, xv.w, acc1[b]))));
    }
  }
#pragma unroll
  for (int b = 0; b < B_; ++b)
#pragma unroll
    for (int s = 32; s; s >>= 1) {
      acc0[b] += __shfl_xor(acc0[b], s);
      acc1[b] += __shfl_xor(acc1[b], s);
    }
  if (l == 0) {
    const int h = r0 / (DN_ + DR_);
    const int j0 = r0 - h * (DN_ + DR_);
    const float b0 = bqb[r0], b1 = bqb[r0 + 1];
    if (j0 < DN_) {
      float* qn = ws + WS_QNOPE;
#pragma unroll
      for (int b = 0; b < B_; ++b) {
        const float sb = ws[WS_QRS + b];
        qn[(b * H_ + h) * DN_ + j0]     = acc0[b] * sb + b0;
        qn[(b * H_ + h) * DN_ + j0 + 1] = acc1[b] * sb + b1;
      }
    } else {
      const int i = (j0 - DN_) >> 1;
      const float c = fcos[i], s = fsin[i];
      float* qT = ws + WS_QT;
#pragma unroll
      for (int b = 0; b < B_; ++b) {
        const float sb = ws[WS_QRS + b];
        const float xr = acc0[b] * sb + b0, xi = acc1[b] * sb + b1;
        qT[((size_t)b * CE_ + KVLR_ + 2 * i) * H_ + h]     = xr * c - xi * s;
        qT[((size_t)b * CE_ + KVLR_ + 2 * i + 1) * H_ + h] = xr * s + xi * c;
      }
    }
  }
}

// ---------------- K4: q_abs[b][c][h] = sum_d q_nope[b][h][d] * wkv_b[h][d][c] ----------------
__global__ __launch_bounds__(256) void mla_k4(const float* __restrict__ wkvb,
                                              float* __restrict__ ws) {
  __shared__ float red[3 * 64 * B_];
  const int h = blockIdx.y;
  const int strip = blockIdx.x;     // 8 strips of 64 cols
  const int tid = threadIdx.x;
  const int c = tid & 63, dg = tid >> 6;  // 4 groups of 32 d
  const int cg = strip * 64 + c;
  const float* qn = ws + WS_QNOPE;
  float acc[B_];
#pragma unroll
  for (int b = 0; b < B_; ++b) acc[b] = 0.f;
  const float* wp = wkvb + (size_t)h * 256 * KVLR_ + cg;
#pragma unroll 4
  for (int dd = 0; dd < 32; ++dd) {
    const int d = dg * 32 + dd;
    const float wv = wp[(size_t)d * KVLR_];
#pragma unroll
    for (int b = 0; b < B_; ++b) acc[b] = fmaf(qn[(b * H_ + h) * DN_ + d], wv, acc[b]);
  }
  if (dg > 0) {
#pragma unroll
    for (int b = 0; b < B_; ++b) red[(((dg - 1) * 64) + c) * B_ + b] = acc[b];
  }
  __syncthreads();
  if (dg == 0) {
    float* qT = ws + WS_QT;
#pragma unroll
    for (int b = 0; b < B_; ++b) {
      const float v = acc[b] + red[c * B_ + b] + red[(64 + c) * B_ + b] + red[(128 + c) * B_ + b];
      qT[((size_t)b * CE_ + cg) * H_ + h] = v;
    }
  }
}

// ---------------- K5: single-pass LDS-staged flash decode per (b, chunk of 128) ----------------
__global__ __launch_bounds__(512, 4) void mla_k5(const float* __restrict__ kvpre,
                                                 const float* __restrict__ pepre,
                                                 float* __restrict__ ws) {
  __shared__ float kvt[TT_ * KSTR_];   // 33.0 KB kv tile (also final merge buffer)
  __shared__ float pet[TT_ * PSTR_];   // 4.3 KB pe tile
  __shared__ float ps[8 * TT_ * 20];   // 10.2 KB partial scores [qg][t'][h pad 20]
  __shared__ float pm[TT_ * 20];       // softmax p [t'][h pad 20]
  __shared__ float mrun[H_], lrun[H_], alf[H_];
  const int b = blockIdx.y, chunk = blockIdx.x;
  const int t0 = chunk * CT_;
  const int tid = threadIdx.x;
  const int l = tid & 63, w = tid >> 6;
  const float* kvnewb = ws + WS_KVNEW + b * KVLR_;
  const float* penewb = ws + WS_PENEW + b * DR_;
  const float* qb = ws + WS_QT + (size_t)b * CE_ * H_;  // [c][16]
  // thread roles
  const int t_s = tid & 15, hq_s = (tid >> 4) & 3, qg = tid >> 6; // scores map
  const int hq_a = w & 3, th_a = w >> 2;                          // accum map
  if (tid < H_) { mrun[tid] = -3.4e38f; lrun[tid] = 0.f; }
  float o[4][8];
#pragma unroll
  for (int a = 0; a < 4; ++a)
#pragma unroll
    for (int j = 0; j < 8; ++j) o[a][j] = 0.f;

  for (int tile = 0; tile < CT_ / TT_; ++tile) {
    const int tbase = t0 + tile * TT_;
    __syncthreads();  // kvt free (prev accum done); covers mrun init on tile 0
    // ---- stage kv/pe tile, fully coalesced ----
#pragma unroll
    for (int k = 0; k < 4; ++k) {
      const int idx = tid + 512 * k;          // float4 index in 16x512 tile
      const int row = idx >> 7, col4 = idx & 127;
      const int tg = tbase + row;
      const float4 v = (tg < TPRE_)
        ? *(const float4*)(kvpre + ((size_t)b * TPRE_ + tg) * KVLR_ + col4 * 4)
        : *(const float4*)(kvnewb + col4 * 4);
      *(float4*)(kvt + row * KSTR_ + col4 * 4) = v;
    }
    if (tid < 256) {
      const int row = tid >> 4, col4 = tid & 15;
      const int tg = tbase + row;
      const float4 v = (tg < TPRE_)
        ? *(const float4*)(pepre + ((size_t)b * TPRE_ + tg) * DR_ + col4 * 4)
        : *(const float4*)(penewb + col4 * 4);
      *(float4*)(pet + row * PSTR_ + col4 * 4) = v;
    }
    __syncthreads();
    // ---- scores: thread = (t' 16, head-quad 4, c-slice 8) ----
    {
      float4 a4; a4.x = 0.f; a4.y = 0.f; a4.z = 0.f; a4.w = 0.f;
      const float* kvrow = kvt + t_s * KSTR_;
      auto acc4 = [&](const float4 k, const float* qc) {
        const float4 q0 = *(const float4*)(qc);
        const float4 q1 = *(const float4*)(qc + H_);
        const float4 q2 = *(const float4*)(qc + 2 * H_);
        const float4 q3 = *(const float4*)(qc + 3 * H_);
        a4.x = fmaf(k.x, q0.x, fmaf(k.y, q1.x, fmaf(k.z, q2.x, fmaf(k.w, q3.x, a4.x))));
        a4.y = fmaf(k.x, q0.y, fmaf(k.y, q1.y, fmaf(k.z, q2.y, fmaf(k.w, q3.y, a4.y))));
        a4.z = fmaf(k.x, q0.z, fmaf(k.y, q1.z, fmaf(k.z, q2.z, fmaf(k.w, q3.z, a4.z))));
        a4.w = fmaf(k.x, q0.w, fmaf(k.y, q1.w, fmaf(k.z, q2.w, fmaf(k.w, q3.w, a4.w))));
      };
      if (qg < 7) {
        const int c0 = qg * 72;
#pragma unroll 3
        for (int i = 0; i < 18; ++i) {
          const float4 k = *(const float4*)(kvrow + c0 + 4 * i);
          acc4(k, qb + (size_t)(c0 + 4 * i) * H_ + 4 * hq_s);
        }
      } else {
#pragma unroll
        for (int i = 0; i < 2; ++i) {   // kv cols 504..511
          const float4 k = *(const float4*)(kvrow + 504 + 4 * i);
          acc4(k, qb + (size_t)(504 + 4 * i) * H_ + 4 * hq_s);
        }
        const float* perow = pet + t_s * PSTR_;
#pragma unroll 4
        for (int i = 0; i < 16; ++i) {  // pe cols
          const float4 k = *(const float4*)(perow + 4 * i);
          acc4(k, qb + (size_t)(KVLR_ + 4 * i) * H_ + 4 * hq_s);
        }
      }
      *(float4*)(ps + (qg * TT_ + t_s) * 20 + 4 * hq_s) = a4;
    }
    __syncthreads();
    // ---- reduce partials + online softmax ----
    if (tid < 256) {
      const int t_ = tid & 15, h = tid >> 4;
      float s = 0.f;
#pragma unroll
      for (int g = 0; g < 8; ++g) s += ps[(g * TT_ + t_) * 20 + h];
      s *= SCALE_;
      float mt = s;
#pragma unroll
      for (int d = 8; d; d >>= 1) mt = fmaxf(mt, __shfl_xor(mt, d, 16));
      const float mprev = mrun[h];
      const float mnew = fmaxf(mprev, mt);
      const float p = __expf(s - mnew);
      float ls = p;
#pragma unroll
      for (int d = 8; d; d >>= 1) ls += __shfl_xor(ls, d, 16);
      pm[t_ * 20 + h] = p;
      if (t_ == 0) {
        const float a = __expf(mprev - mnew);
        alf[h] = a;
        lrun[h] = lrun[h] * a + ls;
        mrun[h] = mnew;
      }
    }
    __syncthreads();
    // ---- accumulate O from LDS tile: wave = (head-quad 4, t-half 2), lane = c/8 ----
    {
      float al[4];
#pragma unroll
      for (int a = 0; a < 4; ++a) al[a] = alf[4 * hq_a + a];
#pragma unroll
      for (int a = 0; a < 4; ++a)
#pragma unroll
        for (int j = 0; j < 8; ++j) o[a][j] *= al[a];
      const int c0 = 8 * l;
#pragma unroll
      for (int tt = 0; tt < 8; ++tt) {
        const int t_ = th_a * 8 + tt;
        const float4 p4 = *(const float4*)(pm + t_ * 20 + 4 * hq_a);
        const float4 k0 = *(const float4*)(kvt + t_ * KSTR_ + c0);
        const float4 k1 = *(const float4*)(kvt + t_ * KSTR_ + c0 + 4);
        o[0][0] = fmaf(p4.x, k0.x, o[0][0]); o[0][1] = fmaf(p4.x, k0.y, o[0][1]);
        o[0][2] = fmaf(p4.x, k0.z, o[0][2]); o[0][3] = fmaf(p4.x, k0.w, o[0][3]);
        o[0][4] = fmaf(p4.x, k1.x, o[0][4]); o[0][5] = fmaf(p4.x, k1.y, o[0][5]);
        o[0][6] = fmaf(p4.x, k1.z, o[0][6]); o[0][7] = fmaf(p4.x, k1.w, o[0][7]);
        o[1][0] = fmaf(p4.y, k0.x, o[1][0]); o[1][1] = fmaf(p4.y, k0.y, o[1][1]);
        o[1][2] = fmaf(p4.y, k0.z, o[1][2]); o[1][3] = fmaf(p4.y, k0.w, o[1][3]);
        o[1][4] = fmaf(p4.y, k1.x, o[1][4]); o[1][5] = fmaf(p4.y, k1.y, o[1][5]);
        o[1][6] = fmaf(p4.y, k1.z, o[1][6]); o[1][7] = fmaf(p4.y, k1.w, o[1][7]);
        o[2][0] = fmaf(p4.z, k0.x, o[2][0]); o[2][1] = fmaf(p4.z, k0.y, o[2][1]);
        o[2][2] = fmaf(p4.z, k0.z, o[2][2]); o[2][3] = fmaf(p4.z, k0.w, o[2][3]);
        o[2][4] = fmaf(p4.z, k1.x, o[2][4]); o[2][5] = fmaf(p4.z, k1.y, o[2][5]);
        o[2][6] = fmaf(p4.z, k1.z, o[2][6]); o[2][7] = fmaf(p4.z, k1.w, o[2][7]);
        o[3][0] = fmaf(p4.w, k0.x, o[3][0]); o[3][1] = fmaf(p4.w, k0.y, o[3][1]);
        o[3][2] = fmaf(p4.w, k0.z, o[3][2]); o[3][3] = fmaf(p4.w, k0.w, o[3][3]);
        o[3][4] = fmaf(p4.w, k1.x, o[3][4]); o[3][5] = fmaf(p4.w, k1.y, o[3][5]);
        o[3][6] = fmaf(p4.w, k1.z, o[3][6]); o[3][7] = fmaf(p4.w, k1.w, o[3][7]);
      }
    }
  }
  __syncthreads();
  // ---- merge the two t-half wave groups (reuse kvt as buffer), write partials ----
  if (w >= 4) {
#pragma unroll
    for (int a = 0; a < 4; ++a) {
      float4 v0; v0.x = o[a][0]; v0.y = o[a][1]; v0.z = o[a][2]; v0.w = o[a][3];
      float4 v1; v1.x = o[a][4]; v1.y = o[a][5]; v1.z = o[a][6]; v1.w = o[a][7];
      *(float4*)(kvt + (size_t)(hq_a * 4 + a) * KVLR_ + 8 * l)     = v0;
      *(float4*)(kvt + (size_t)(hq_a * 4 + a) * KVLR_ + 8 * l + 4) = v1;
    }
  }
  __syncthreads();
  if (w < 4) {
#pragma unroll
    for (int a = 0; a < 4; ++a) {
      const int h = hq_a * 4 + a;
      const float4 u0 = *(const float4*)(kvt + (size_t)h * KVLR_ + 8 * l);
      const float4 u1 = *(const float4*)(kvt + (size_t)h * KVLR_ + 8 * l + 4);
      float4 v0; v0.x = o[a][0] + u0.x; v0.y = o[a][1] + u0.y; v0.z = o[a][2] + u0.z; v0.w = o[a][3] + u0.w;
      float4 v1; v1.x = o[a][4] + u1.x; v1.y = o[a][5] + u1.y; v1.z = o[a][6] + u1.z; v1.w = o[a][7] + u1.w;
      float* Op = ws + WS_OPART + (((size_t)(b * H_ + h) * NCH_ + chunk) * KVLR_);
      *(float4*)(Op + 8 * l)     = v0;
      *(float4*)(Op + 8 * l + 4) = v1;
    }
  }
  if (tid < H_) {
    ws[WS_MLOC + (b * H_ + tid) * NCH_ + chunk] = mrun[tid];
    ws[WS_LLOC + (b * H_ + tid) * NCH_ + chunk] = lrun[tid];
  }
}

// ---------------- K6: combine partials + project through wkv_b[:,128:,:] ----------------
__global__ __launch_bounds__(256) void mla_k6(const float* __restrict__ wkvb,
                                              float* __restrict__ ws) {
  const int h = blockIdx.x, b = blockIdx.y;
  __shared__ float wgt[NCH_];
  __shared__ float ao[KVLR_];
  __shared__ float Linv;
  const int tid = threadIdx.x;
  if (tid < NCH_) { // one full wave
    const float m = ws[WS_MLOC + (b * H_ + h) * NCH_ + tid];
    float M = m;
#pragma unroll
    for (int s = 32; s; s >>= 1) M = fmaxf(M, __shfl_xor(M, s));
    const float wv = __expf(m - M);
    wgt[tid] = wv;
    float lv = ws[WS_LLOC + (b * H_ + h) * NCH_ + tid] * wv;
#pragma unroll
    for (int s = 32; s; s >>= 1) lv += __shfl_xor(lv, s);
    if (tid == 0) Linv = 1.0f / lv;
  }
  __syncthreads();
  const float* Ob = ws + WS_OPART + (size_t)(b * H_ + h) * NCH_ * KVLR_;
  float s0 = 0.f, s1 = 0.f;
#pragma unroll 4
  for (int i = 0; i < NCH_; ++i) {
    const float wv = wgt[i];
    s0 = fmaf(wv, Ob[(size_t)i * KVLR_ + tid], s0);
    s1 = fmaf(wv, Ob[(size_t)i * KVLR_ + tid + 256], s1);
  }
  const float li = Linv;
  ao[tid] = s0 * li;
  ao[tid + 256] = s1 * li;
  __syncthreads();
  const int v = tid >> 1, half = tid & 1;
  const float* w2 = wkvb + ((size_t)h * 256 + DN_ + v) * KVLR_ + half * 256;
  const float* a = ao + half * 256;
  float s = 0.f;
#pragma unroll
  for (int c = 0; c < 256; c += 4) {
    const float4 wv = *(const float4*)(w2 + c);
    s = fmaf(wv.x, a[c], s);
    s = fmaf(wv.y, a[c + 1], s);
    s = fmaf(wv.z, a[c + 2], s);
    s = fmaf(wv.w, a[c + 3], s);
  }
  s += __shfl_xor(s, 1);
  if (half == 0) ws[WS_OUT2 + b * DIM_ + h * DV_ + v] = s;
}

// ---------------- K7: y = out2 @ wo^T + wo_b ----------------
__global__ __launch_bounds__(512) void mla_k7(const float* __restrict__ wo,
                                              const float* __restrict__ wob,
                                              const float* __restrict__ ws,
                                              float* __restrict__ out) {
  const int w = threadIdx.x >> 6, l = threadIdx.x & 63;
  const int r = blockIdx.x * 8 + w;  // 0..2047
  const float4* wp = (const float4*)(wo + (size_t)r * DIM_);
  const float4* x4 = (const float4*)(ws + WS_OUT2);
  float4 wv[8];
#pragma unroll
  for (int j = 0; j < 8; ++j) wv[j] = wp[l + 64 * j];
  float acc[B_];
#pragma unroll
  for (int b = 0; b < B_; ++b) acc[b] = 0.f;
#pragma unroll
  for (int b = 0; b < B_; ++b) {
#pragma unroll
    for (int j = 0; j < 8; ++j) {
      const float4 xv = x4[b * (DIM_ / 4) + l + 64 * j];
      acc[b] = fmaf(wv[j].x, xv.x, fmaf(wv[j].y, xv.y, fmaf(wv[j].z, xv.z, fmaf(wv[j].w, xv.w, acc[b]))));
    }
  }
#pragma unroll
  for (int b = 0; b < B_; ++b)
#pragma unroll
    for (int s = 32; s; s >>= 1) acc[b] += __shfl_xor(acc[b], s);
  if (l == 0) {
    const float b0 = wob[r];
#pragma unroll
    for (int b = 0; b < B_; ++b) out[b * DIM_ + r] = acc[b] + b0;
  }
}

extern "C" void kernel_launch(void* const* d_in, const int* in_sizes, int n_in,
                              void* d_out, int out_size, void* d_ws, size_t ws_size,
                              hipStream_t stream) {
  (void)in_sizes; (void)n_in; (void)out_size; (void)ws_size;
  const float* x     = (const float*)d_in[0];
  const float* fcos  = (const float*)d_in[2];
  const float* fsin  = (const float*)d_in[3];
  const float* kvpre = (const float*)d_in[4];
  const float* pepre = (const float*)d_in[5];
  const float* wqa   = (const float*)d_in[6];
  const float* bqa   = (const float*)d_in[7];
  const float* qnw   = (const float*)d_in[8];
  const float* wqb   = (const float*)d_in[9];
  const float* bqb   = (const float*)d_in[10];
  const float* wkva  = (const float*)d_in[11];
  const float* bkva  = (const float*)d_in[12];
  const float* kvnw  = (const float*)d_in[13];
  const float* wkvb  = (const float*)d_in[14];
  const float* wo    = (const float*)d_in[15];
  const float* wob   = (const float*)d_in[16];
  float* ws  = (float*)d_ws;
  float* out = (float*)d_out;

  mla_k1<<<dim3((QLR_ + CE_) / 8), dim3(512), 0, stream>>>(x, wqa, bqa, wkva, bkva, ws);
  mla_k2<<<dim3(1), dim3(256), 0, stream>>>(kvnw, fcos, fsin, ws);
  mla_k3<<<dim3(H_ * (DN_ + DR_) / 8), dim3(256), 0, stream>>>(qnw, wqb, bqb, fcos, fsin, ws);
  mla_k4<<<dim3(8, H_), dim3(256), 0, stream>>>(wkvb, ws);
  mla_k5<<<dim3(NCH_, B_), dim3(512), 0, stream>>>(kvpre, pepre, ws);
  mla_k6<<<dim3(H_, B_), dim3(256), 0, stream>>>(wkvb, ws);
  mla_k7<<<dim3(DIM_ / 8), dim3(512), 0, stream>>>(wo, wob, ws, out);
}

// Round 4
// 411.104 us; speedup vs baseline: 1.0925x; 1.0925x over previous
//
#include <hip/hip_runtime.h>
#include <math.h>

namespace {
constexpr int B_   = 8;
constexpr int DIM_ = 2048;
constexpr int H_   = 16;
constexpr int QLR_ = 1536;
constexpr int KVLR_= 512;
constexpr int DN_  = 128;
constexpr int DR_  = 64;
constexpr int DV_  = 128;
constexpr int TPRE_= 8191;
constexpr int CE_  = 576;    // KVLR + DR
constexpr int NCH_ = 32;     // chunks over T=8192
constexpr int CT_  = 256;    // t per chunk
constexpr float EPS_ = 1e-6f;
constexpr float SCALE_ = 0.07216878364870322f; // (DN+DR)^-0.5
constexpr int SSTR_ = 20;    // padded LDS stride for score tile [256][20]

// workspace layout (float offsets)
constexpr size_t WS_QLAT  = 0;
constexpr size_t WS_KVPE  = WS_QLAT  + (size_t)B_*QLR_;
constexpr size_t WS_KVNEW = WS_KVPE  + (size_t)B_*CE_;
constexpr size_t WS_PENEW = WS_KVNEW + (size_t)B_*KVLR_;
constexpr size_t WS_QRS   = WS_PENEW + (size_t)B_*DR_;
constexpr size_t WS_QNOPE = WS_QRS   + (size_t)B_;
constexpr size_t WS_QT    = WS_QNOPE + (size_t)B_*H_*DN_;   // [b][576][16]
constexpr size_t WS_MLOC  = WS_QT    + (size_t)B_*CE_*H_;
constexpr size_t WS_LLOC  = WS_MLOC  + (size_t)B_*H_*NCH_;
constexpr size_t WS_OUT2  = WS_LLOC  + (size_t)B_*H_*NCH_;
constexpr size_t WS_OPART = WS_OUT2  + (size_t)B_*DIM_;     // [b][h][chunk][512]
} // namespace

// ---------------- K1: q_latent = x@wq_a^T + b ; kvpe = x@wkv_a^T + b ----------------
// 256-thr blocks, 1 row/wave, grid 528 (>=2 blocks/CU).
__global__ __launch_bounds__(256) void mla_k1(const float* __restrict__ x,
                                              const float* __restrict__ wqa,
                                              const float* __restrict__ bqa,
                                              const float* __restrict__ wkva,
                                              const float* __restrict__ bkva,
                                              float* __restrict__ ws) {
  const int w = threadIdx.x >> 6, l = threadIdx.x & 63;
  const int r = blockIdx.x * 4 + w;  // 0..2111
  const float* W; const float* bias; float* out; int rr; int ostride;
  if (r < QLR_) { W = wqa;  bias = bqa;  out = ws + WS_QLAT; rr = r;        ostride = QLR_; }
  else          { W = wkva; bias = bkva; out = ws + WS_KVPE; rr = r - QLR_; ostride = CE_;  }
  const float4* wp = (const float4*)(W + (size_t)rr * DIM_);
  const float4* x4 = (const float4*)x;
  float4 wv[8];
#pragma unroll
  for (int j = 0; j < 8; ++j) wv[j] = wp[l + 64 * j];  // independent weight stream first
  float acc[B_];
#pragma unroll
  for (int b = 0; b < B_; ++b) acc[b] = 0.f;
#pragma unroll
  for (int b = 0; b < B_; ++b) {
#pragma unroll
    for (int j = 0; j < 8; ++j) {
      const float4 xv = x4[b * (DIM_ / 4) + l + 64 * j];
      acc[b] = fmaf(wv[j].x, xv.x, fmaf(wv[j].y, xv.y, fmaf(wv[j].z, xv.z, fmaf(wv[j].w, xv.w, acc[b]))));
    }
  }
#pragma unroll
  for (int b = 0; b < B_; ++b)
#pragma unroll
    for (int s = 32; s; s >>= 1) acc[b] += __shfl_xor(acc[b], s);
  if (l == 0) {
    const float b0 = bias[rr];
#pragma unroll
    for (int b = 0; b < B_; ++b) out[b * ostride + rr] = acc[b] + b0;
  }
}

// ---------------- K2: kv rms-norm + k_pe rope + q rms scales ----------------
__global__ __launch_bounds__(256) void mla_k2(const float* __restrict__ kvnw,
                                              const float* __restrict__ fcos,
                                              const float* __restrict__ fsin,
                                              float* __restrict__ ws) {
  const int tid = threadIdx.x;
  const int b = tid >> 5, i = tid & 31;
  const float* kvpe = ws + WS_KVPE + b * CE_;
  float ss = 0.f;
#pragma unroll
  for (int j = 0; j < KVLR_ / 32; ++j) { const float v = kvpe[i + 32 * j]; ss = fmaf(v, v, ss); }
#pragma unroll
  for (int s = 16; s; s >>= 1) ss += __shfl_xor(ss, s, 32);
  const float scale = 1.0f / sqrtf(ss / (float)KVLR_ + EPS_);
  float* kvn = ws + WS_KVNEW + b * KVLR_;
#pragma unroll
  for (int j = 0; j < KVLR_ / 32; ++j) {
    const int c = i + 32 * j;
    kvn[c] = kvpe[c] * kvnw[c] * scale;
  }
  { // rope new k_pe
    const float xr = kvpe[KVLR_ + 2 * i], xi = kvpe[KVLR_ + 2 * i + 1];
    const float c = fcos[i], s = fsin[i];
    float* pen = ws + WS_PENEW + b * DR_;
    pen[2 * i]     = xr * c - xi * s;
    pen[2 * i + 1] = xr * s + xi * c;
  }
  { // q latent rms scale per batch
    const float* p = ws + WS_QLAT + b * QLR_;
    float sq = 0.f;
#pragma unroll
    for (int j = 0; j < QLR_ / 32; ++j) { const float v = p[i + 32 * j]; sq = fmaf(v, v, sq); }
#pragma unroll
    for (int s = 16; s; s >>= 1) sq += __shfl_xor(sq, s, 32);
    if (i == 0) ws[WS_QRS + b] = 1.0f / sqrtf(sq / (float)QLR_ + EPS_);
  }
}

// ---------------- K3: q = rms(q_lat)*g @ wq_b^T + b ; split nope / rope(pe) ----------------
__global__ __launch_bounds__(256) void mla_k3(const float* __restrict__ qnw,
                                              const float* __restrict__ wqb,
                                              const float* __restrict__ bqb,
                                              const float* __restrict__ fcos,
                                              const float* __restrict__ fsin,
                                              float* __restrict__ ws) {
  const int w = threadIdx.x >> 6, l = threadIdx.x & 63;
  const int r0 = blockIdx.x * 8 + w * 2;  // 0..3070
  const float4* w0p = (const float4*)(wqb + (size_t)r0 * QLR_);
  const float4* w1p = (const float4*)(wqb + (size_t)(r0 + 1) * QLR_);
  const float4* g4  = (const float4*)qnw;
  const float4* x4  = (const float4*)(ws + WS_QLAT);
  float4 wg0[6], wg1[6];
#pragma unroll
  for (int j = 0; j < 6; ++j) {       // preload weights*gain
    const int c4 = l + 64 * j;
    const float4 a = w0p[c4], bb = w1p[c4], g = g4[c4];
    wg0[j].x = a.x * g.x; wg0[j].y = a.y * g.y; wg0[j].z = a.z * g.z; wg0[j].w = a.w * g.w;
    wg1[j].x = bb.x * g.x; wg1[j].y = bb.y * g.y; wg1[j].z = bb.z * g.z; wg1[j].w = bb.w * g.w;
  }
  float acc0[B_], acc1[B_];
#pragma unroll
  for (int b = 0; b < B_; ++b) { acc0[b] = 0.f; acc1[b] = 0.f; }
#pragma unroll
  for (int b = 0; b < B_; ++b) {
#pragma unroll
    for (int j = 0; j < 6; ++j) {
      const float4 xv = x4[b * (QLR_ / 4) + l + 64 * j];
      acc0[b] = fmaf(wg0[j].x, xv.x, fmaf(wg0[j].y, xv.y, fmaf(wg0[j].z, xv.z, fmaf(wg0[j].w, xv.w, acc0[b]))));
      acc1[b] = fmaf(wg1[j].x, xv.x, fmaf(wg1[j].y, xv.y, fmaf(wg1[j].z, xv.z, fmaf(wg1[j].w, xv.w, acc1[b]))));
    }
  }
#pragma unroll
  for (int b = 0; b < B_; ++b)
#pragma unroll
    for (int s = 32; s; s >>= 1) {
      acc0[b] += __shfl_xor(acc0[b], s);
      acc1[b] += __shfl_xor(acc1[b], s);
    }
  if (l == 0) {
    const int h = r0 / (DN_ + DR_);
    const int j0 = r0 - h * (DN_ + DR_);
    const float b0 = bqb[r0], b1 = bqb[r0 + 1];
    if (j0 < DN_) {
      float* qn = ws + WS_QNOPE;
#pragma unroll
      for (int b = 0; b < B_; ++b) {
        const float sb = ws[WS_QRS + b];
        qn[(b * H_ + h) * DN_ + j0]     = acc0[b] * sb + b0;
        qn[(b * H_ + h) * DN_ + j0 + 1] = acc1[b] * sb + b1;
      }
    } else {
      const int i = (j0 - DN_) >> 1;
      const float c = fcos[i], s = fsin[i];
      float* qT = ws + WS_QT;
#pragma unroll
      for (int b = 0; b < B_; ++b) {
        const float sb = ws[WS_QRS + b];
        const float xr = acc0[b] * sb + b0, xi = acc1[b] * sb + b1;
        qT[((size_t)b * CE_ + KVLR_ + 2 * i) * H_ + h]     = xr * c - xi * s;
        qT[((size_t)b * CE_ + KVLR_ + 2 * i + 1) * H_ + h] = xr * s + xi * c;
      }
    }
  }
}

// ---------------- K4: q_abs[b][c][h] = sum_d q_nope[b][h][d] * wkv_b[h][d][c] ----------------
// grid (16 strips x 16 h) = 256 blocks of 256 thr: 32 c x 8 d-groups of 16.
__global__ __launch_bounds__(256) void mla_k4(const float* __restrict__ wkvb,
                                              float* __restrict__ ws) {
  __shared__ float red[7 * 32 * B_];
  const int h = blockIdx.y;
  const int strip = blockIdx.x;     // 16 strips of 32 cols
  const int tid = threadIdx.x;
  const int c = tid & 31, dg = tid >> 5;  // 8 groups of 16 d
  const int cg = strip * 32 + c;
  const float* qn = ws + WS_QNOPE;
  float acc[B_];
#pragma unroll
  for (int b = 0; b < B_; ++b) acc[b] = 0.f;
  const float* wp = wkvb + (size_t)h * 256 * KVLR_ + cg;
#pragma unroll
  for (int dd = 0; dd < 16; ++dd) {
    const int d = dg * 16 + dd;
    const float wv = wp[(size_t)d * KVLR_];
#pragma unroll
    for (int b = 0; b < B_; ++b) acc[b] = fmaf(qn[(b * H_ + h) * DN_ + d], wv, acc[b]);
  }
  if (dg > 0) {
#pragma unroll
    for (int b = 0; b < B_; ++b) red[(((dg - 1) * 32) + c) * B_ + b] = acc[b];
  }
  __syncthreads();
  if (dg == 0) {
    float* qT = ws + WS_QT;
#pragma unroll
    for (int b = 0; b < B_; ++b) {
      float v = acc[b];
#pragma unroll
      for (int g = 0; g < 7; ++g) v += red[(g * 32 + c) * B_ + b];
      qT[((size_t)b * CE_ + cg) * H_ + h] = v;
    }
  }
}

// ---------------- K5: flash-decode partials per (b, chunk) — R1 structure + deep unroll ----------------
__global__ __launch_bounds__(256) void mla_k5(const float* __restrict__ kvpre,
                                              const float* __restrict__ pepre,
                                              float* __restrict__ ws) {
  __shared__ float sl[CT_ * SSTR_]; // 20 KB scores -> p
  const int b = blockIdx.y;
  const int chunk = blockIdx.x;
  const int t0 = chunk * CT_;
  const int tid = threadIdx.x;
  const int w = tid >> 6, l = tid & 63;
  const float* kvnew = ws + WS_KVNEW;
  const float* penew = ws + WS_PENEW;

  // ---- phase A: scores, lane <-> t, q via wave-uniform scalar loads; 4 loads in flight ----
  {
    const int t = t0 + (w << 6) + l;
    const float* kvrow; const float* perow;
    if (t < TPRE_) {
      kvrow = kvpre + ((size_t)b * TPRE_ + t) * KVLR_;
      perow = pepre + ((size_t)b * TPRE_ + t) * DR_;
    } else {
      kvrow = kvnew + b * KVLR_;
      perow = penew + b * DR_;
    }
    const float* qTb = ws + WS_QT + (size_t)b * CE_ * H_;
    float acc[H_];
#pragma unroll
    for (int h = 0; h < H_; ++h) acc[h] = 0.f;
    auto fma4 = [&](const float4 k, const float* qc) {
#pragma unroll
      for (int h = 0; h < H_; ++h) {
        acc[h] = fmaf(qc[h],          k.x, acc[h]);
        acc[h] = fmaf(qc[H_ + h],     k.y, acc[h]);
        acc[h] = fmaf(qc[2 * H_ + h], k.z, acc[h]);
        acc[h] = fmaf(qc[3 * H_ + h], k.w, acc[h]);
      }
    };
    for (int c16 = 0; c16 < KVLR_; c16 += 16) {   // 32 iters, 4 hoisted loads each
      const float4 k0 = *(const float4*)(kvrow + c16);
      const float4 k1 = *(const float4*)(kvrow + c16 + 4);
      const float4 k2 = *(const float4*)(kvrow + c16 + 8);
      const float4 k3 = *(const float4*)(kvrow + c16 + 12);
      const float* qc = qTb + (size_t)c16 * H_;
      fma4(k0, qc);
      fma4(k1, qc + 4 * H_);
      fma4(k2, qc + 8 * H_);
      fma4(k3, qc + 12 * H_);
    }
    {
      const float4 k0 = *(const float4*)(perow);
      const float4 k1 = *(const float4*)(perow + 4);
      const float4 k2 = *(const float4*)(perow + 8);
      const float4 k3 = *(const float4*)(perow + 12);
      const float4 k4 = *(const float4*)(perow + 16);
      const float4 k5 = *(const float4*)(perow + 20);
      const float4 k6 = *(const float4*)(perow + 24);
      const float4 k7 = *(const float4*)(perow + 28);
      const float* qc = qTb + (size_t)KVLR_ * H_;
      fma4(k0, qc);            fma4(k1, qc + 4 * H_);
      fma4(k2, qc + 8 * H_);   fma4(k3, qc + 12 * H_);
      fma4(k4, qc + 16 * H_);  fma4(k5, qc + 20 * H_);
      fma4(k6, qc + 24 * H_);  fma4(k7, qc + 28 * H_);
      const float4 k8 = *(const float4*)(perow + 32);
      const float4 k9 = *(const float4*)(perow + 36);
      const float4 ka = *(const float4*)(perow + 40);
      const float4 kb = *(const float4*)(perow + 44);
      const float4 kc = *(const float4*)(perow + 48);
      const float4 kd = *(const float4*)(perow + 52);
      const float4 ke = *(const float4*)(perow + 56);
      const float4 kf = *(const float4*)(perow + 60);
      fma4(k8, qc + 32 * H_);  fma4(k9, qc + 36 * H_);
      fma4(ka, qc + 40 * H_);  fma4(kb, qc + 44 * H_);
      fma4(kc, qc + 48 * H_);  fma4(kd, qc + 52 * H_);
      fma4(ke, qc + 56 * H_);  fma4(kf, qc + 60 * H_);
    }
    const int tl = (w << 6) + l;
#pragma unroll
    for (int g = 0; g < 4; ++g) {
      float4 v;
      v.x = acc[4 * g] * SCALE_; v.y = acc[4 * g + 1] * SCALE_;
      v.z = acc[4 * g + 2] * SCALE_; v.w = acc[4 * g + 3] * SCALE_;
      *(float4*)(sl + tl * SSTR_ + 4 * g) = v;
    }
  }
  __syncthreads();

  // ---- phase B: chunk-local softmax per head ----
  {
    const int h2 = tid >> 4, grp = tid & 15;
    float m = -3.4e38f;
#pragma unroll
    for (int j = 0; j < 16; ++j) m = fmaxf(m, sl[(grp + 16 * j) * SSTR_ + h2]);
#pragma unroll
    for (int s = 8; s; s >>= 1) m = fmaxf(m, __shfl_xor(m, s, 16));
    float lsum = 0.f;
#pragma unroll
    for (int j = 0; j < 16; ++j) {
      const int idx = (grp + 16 * j) * SSTR_ + h2;
      const float p = __expf(sl[idx] - m);
      sl[idx] = p;
      lsum += p;
    }
#pragma unroll
    for (int s = 8; s; s >>= 1) lsum += __shfl_xor(lsum, s, 16);
    if (grp == 0) {
      ws[WS_MLOC + (b * H_ + h2) * NCH_ + chunk] = m;
      ws[WS_LLOC + (b * H_ + h2) * NCH_ + chunk] = lsum;
    }
  }
  __syncthreads();

  // ---- phase C: O_partial = sum_t p * kv  (wave <-> 4 heads, lanes <-> c, coalesced) ----
  {
    float o[4][8];
#pragma unroll
    for (int a = 0; a < 4; ++a)
#pragma unroll
      for (int j = 0; j < 8; ++j) o[a][j] = 0.f;
    const int hb = w * 4;
    const float* kvb = kvpre + (size_t)b * TPRE_ * KVLR_;
    auto step = [&](const float* kr, int t) {
      const float4 p = *(const float4*)(sl + t * SSTR_ + hb);
#pragma unroll
      for (int j = 0; j < 4; ++j) {
        const float2 kv = *(const float2*)(kr + j * 128 + 2 * l);
        o[0][2 * j]     = fmaf(p.x, kv.x, o[0][2 * j]);
        o[0][2 * j + 1] = fmaf(p.x, kv.y, o[0][2 * j + 1]);
        o[1][2 * j]     = fmaf(p.y, kv.x, o[1][2 * j]);
        o[1][2 * j + 1] = fmaf(p.y, kv.y, o[1][2 * j + 1]);
        o[2][2 * j]     = fmaf(p.z, kv.x, o[2][2 * j]);
        o[2][2 * j + 1] = fmaf(p.z, kv.y, o[2][2 * j + 1]);
        o[3][2 * j]     = fmaf(p.w, kv.x, o[3][2 * j]);
        o[3][2 * j + 1] = fmaf(p.w, kv.y, o[3][2 * j + 1]);
      }
    };
    if (t0 + CT_ <= TPRE_) {
#pragma unroll 4
      for (int t = 0; t < CT_; ++t) step(kvb + (size_t)(t0 + t) * KVLR_, t);
    } else {
      const float* kvn = kvnew + b * KVLR_;
      for (int t = 0; t < CT_; ++t) {
        const float* kr = (t0 + t < TPRE_) ? (kvb + (size_t)(t0 + t) * KVLR_) : kvn;
        step(kr, t);
      }
    }
    float* Op = ws + WS_OPART;
#pragma unroll
    for (int a = 0; a < 4; ++a) {
#pragma unroll
      for (int j = 0; j < 4; ++j) {
        float2 v; v.x = o[a][2 * j]; v.y = o[a][2 * j + 1];
        *(float2*)(Op + (((size_t)(b * H_ + hb + a) * NCH_ + chunk) * KVLR_) + j * 128 + 2 * l) = v;
      }
    }
  }
}

// ---------------- K6: combine partials + project through wkv_b[:,128:,:] ----------------
__global__ __launch_bounds__(256) void mla_k6(const float* __restrict__ wkvb,
                                              float* __restrict__ ws) {
  const int h = blockIdx.x, b = blockIdx.y;
  __shared__ float wgt[NCH_];
  __shared__ float ao[KVLR_];
  __shared__ float Linv;
  const int tid = threadIdx.x;
  if (tid < NCH_) {
    const float m = ws[WS_MLOC + (b * H_ + h) * NCH_ + tid];
    float M = m;
#pragma unroll
    for (int s = 16; s; s >>= 1) M = fmaxf(M, __shfl_xor(M, s, 32));
    const float wv = __expf(m - M);
    wgt[tid] = wv;
    float lv = ws[WS_LLOC + (b * H_ + h) * NCH_ + tid] * wv;
#pragma unroll
    for (int s = 16; s; s >>= 1) lv += __shfl_xor(lv, s, 32);
    if (tid == 0) Linv = 1.0f / lv;
  }
  __syncthreads();
  const float* Ob = ws + WS_OPART + (size_t)(b * H_ + h) * NCH_ * KVLR_;
  float s0 = 0.f, s1 = 0.f;
#pragma unroll 4
  for (int i = 0; i < NCH_; ++i) {
    const float wv = wgt[i];
    s0 = fmaf(wv, Ob[(size_t)i * KVLR_ + tid], s0);
    s1 = fmaf(wv, Ob[(size_t)i * KVLR_ + tid + 256], s1);
  }
  const float li = Linv;
  ao[tid] = s0 * li;
  ao[tid + 256] = s1 * li;
  __syncthreads();
  const int v = tid >> 1, half = tid & 1;
  const float* w2 = wkvb + ((size_t)h * 256 + DN_ + v) * KVLR_ + half * 256;
  const float* a = ao + half * 256;
  float s = 0.f;
#pragma unroll
  for (int c = 0; c < 256; c += 4) {
    const float4 wv = *(const float4*)(w2 + c);
    s = fmaf(wv.x, a[c], s);
    s = fmaf(wv.y, a[c + 1], s);
    s = fmaf(wv.z, a[c + 2], s);
    s = fmaf(wv.w, a[c + 3], s);
  }
  s += __shfl_xor(s, 1);
  if (half == 0) ws[WS_OUT2 + b * DIM_ + h * DV_ + v] = s;
}

// ---------------- K7: y = out2 @ wo^T + wo_b ----------------
// 256-thr blocks, 1 row/wave, grid 512 (2 blocks/CU).
__global__ __launch_bounds__(256) void mla_k7(const float* __restrict__ wo,
                                              const float* __restrict__ wob,
                                              const float* __restrict__ ws,
                                              float* __restrict__ out) {
  const int w = threadIdx.x >> 6, l = threadIdx.x & 63;
  const int r = blockIdx.x * 4 + w;  // 0..2047
  const float4* wp = (const float4*)(wo + (size_t)r * DIM_);
  const float4* x4 = (const float4*)(ws + WS_OUT2);
  float4 wv[8];
#pragma unroll
  for (int j = 0; j < 8; ++j) wv[j] = wp[l + 64 * j];
  float acc[B_];
#pragma unroll
  for (int b = 0; b < B_; ++b) acc[b] = 0.f;
#pragma unroll
  for (int b = 0; b < B_; ++b) {
#pragma unroll
    for (int j = 0; j < 8; ++j) {
      const float4 xv = x4[b * (DIM_ / 4) + l + 64 * j];
      acc[b] = fmaf(wv[j].x, xv.x, fmaf(wv[j].y, xv.y, fmaf(wv[j].z, xv.z, fmaf(wv[j].w, xv.w, acc[b]))));
    }
  }
#pragma unroll
  for (int b = 0; b < B_; ++b)
#pragma unroll
    for (int s = 32; s; s >>= 1) acc[b] += __shfl_xor(acc[b], s);
  if (l == 0) {
    const float b0 = wob[r];
#pragma unroll
    for (int b = 0; b < B_; ++b) out[b * DIM_ + r] = acc[b] + b0;
  }
}

extern "C" void kernel_launch(void* const* d_in, const int* in_sizes, int n_in,
                              void* d_out, int out_size, void* d_ws, size_t ws_size,
                              hipStream_t stream) {
  (void)in_sizes; (void)n_in; (void)out_size; (void)ws_size;
  const float* x     = (const float*)d_in[0];
  const float* fcos  = (const float*)d_in[2];
  const float* fsin  = (const float*)d_in[3];
  const float* kvpre = (const float*)d_in[4];
  const float* pepre = (const float*)d_in[5];
  const float* wqa   = (const float*)d_in[6];
  const float* bqa   = (const float*)d_in[7];
  const float* qnw   = (const float*)d_in[8];
  const float* wqb   = (const float*)d_in[9];
  const float* bqb   = (const float*)d_in[10];
  const float* wkva  = (const float*)d_in[11];
  const float* bkva  = (const float*)d_in[12];
  const float* kvnw  = (const float*)d_in[13];
  const float* wkvb  = (const float*)d_in[14];
  const float* wo    = (const float*)d_in[15];
  const float* wob   = (const float*)d_in[16];
  float* ws  = (float*)d_ws;
  float* out = (float*)d_out;

  mla_k1<<<dim3((QLR_ + CE_) / 4), dim3(256), 0, stream>>>(x, wqa, bqa, wkva, bkva, ws);
  mla_k2<<<dim3(1), dim3(256), 0, stream>>>(kvnw, fcos, fsin, ws);
  mla_k3<<<dim3(H_ * (DN_ + DR_) / 8), dim3(256), 0, stream>>>(qnw, wqb, bqb, fcos, fsin, ws);
  mla_k4<<<dim3(16, H_), dim3(256), 0, stream>>>(wkvb, ws);
  mla_k5<<<dim3(NCH_, B_), dim3(256), 0, stream>>>(kvpre, pepre, ws);
  mla_k6<<<dim3(H_, B_), dim3(256), 0, stream>>>(wkvb, ws);
  mla_k7<<<dim3(DIM_ / 4), dim3(256), 0, stream>>>(wo, wob, ws, out);
}